// Round 3
// baseline (3572.040 us; speedup 1.0000x reference)
//
#include <hip/hip_runtime.h>
#include <hip/hip_bf16.h>
#include <hip/hip_fp16.h>
#include <stdint.h>

// ============================================================================
// LSTMEncoder (3-layer Keras LSTM, per-gate input dropout 0.6, threefry RNG)
//   L0: x[256,1024,128] -> h0 ; L1: h0 -> h1 ; L2: h1 -> h_last[256,64] (f32)
// Round 3: RNG fix — modern JAX defaults jax_threefry_partitionable=True:
//   split(key,3) foldlike:  dk_l = threefry2x32((0,4347),(0,l))
//   random_bits partitionable: bits_i = y0^y1, (y0,y1)=threefry2x32(dk_l,(0,i))
// (rounds 1-2 used the legacy iota-halves scheme -> masks wrong -> absmax 0.23)
//   K2 masks : dropout masks 3 x [4,256,128], values {0, 2.5}
//   K3 gemm  : z[b,t,g*U+u] = sum_d (A[b,t,d]*mask[g,b,d])*Wk[d,g*U+u] + b
//              f32 FMA, LDS-tiled, f16 z to workspace
//   K4 rec   : persistent recurrence, 1 WG per batch row (rows independent),
//              Wr column in VGPRs, h broadcast via LDS, f32 math.
// Workspace: masks(1.5MB) + z_in f16(256MB) + h0,h1 f16(64MB ea)  ~= 404MB
// ============================================================================

#define MODE_F32  0
#define MODE_F16  2

// ---------------- dtype helpers ----------------
template<int M>
__device__ __forceinline__ void cvt8(const void* p, size_t i, float* o){
  if constexpr (M == MODE_F32){
    const float* f = (const float*)p + i;
    float4 a = *(const float4*)f;
    float4 b = *(const float4*)(f + 4);
    o[0]=a.x; o[1]=a.y; o[2]=a.z; o[3]=a.w;
    o[4]=b.x; o[5]=b.y; o[6]=b.z; o[7]=b.w;
  } else {
    uint4 r = *(const uint4*)((const uint16_t*)p + i);
    uint32_t hw[4] = {r.x, r.y, r.z, r.w};
    #pragma unroll
    for (int q=0;q<4;q++){
      __half_raw lo; lo.x = (unsigned short)(hw[q] & 0xffffu);
      __half_raw hi; hi.x = (unsigned short)(hw[q] >> 16);
      o[2*q]   = __half2float(__half(lo));
      o[2*q+1] = __half2float(__half(hi));
    }
  }
}

// ---------------- K2: JAX threefry2x32 (partitionable) masks ----------------
__device__ __forceinline__ void tf2x32(uint32_t k0, uint32_t k1,
                                       uint32_t& x0, uint32_t& x1){
  uint32_t ks2 = k0 ^ k1 ^ 0x1BD11BDAu;
  x0 += k0; x1 += k1;
#define TF_R(r) { x0 += x1; x1 = (x1<<r)|(x1>>(32-r)); x1 ^= x0; }
  TF_R(13) TF_R(15) TF_R(26) TF_R(6)  x0 += k1;  x1 += ks2 + 1u;
  TF_R(17) TF_R(29) TF_R(16) TF_R(24) x0 += ks2; x1 += k0  + 2u;
  TF_R(13) TF_R(15) TF_R(26) TF_R(6)  x0 += k0;  x1 += k1  + 3u;
  TF_R(17) TF_R(29) TF_R(16) TF_R(24) x0 += k1;  x1 += ks2 + 4u;
  TF_R(13) TF_R(15) TF_R(26) TF_R(6)  x0 += ks2; x1 += k0  + 5u;
#undef TF_R
}

__device__ __forceinline__ float bern_mask(uint32_t bits){
  // jax uniform: bitcast((bits>>9)|0x3f800000) - 1.0 ; keep if < 0.4 ; /0.4
  float u = __uint_as_float((bits >> 9) | 0x3f800000u) - 1.0f;
  return (u < 0.4f) ? 2.5f : 0.0f;
}

// one thread per mask element; 3 layers x 131072 elements
__global__ void mask_kernel(float* __restrict__ masks){
  int gid = blockIdx.x * 256 + threadIdx.x;     // [0, 3*131072)
  int layer = gid >> 17;
  uint32_t i = (uint32_t)(gid & 131071);
  // split(key(4347), 3), foldlike: dk_l = threefry2x32((0,4347), (0, l))
  uint32_t k0 = 0u, k1 = (uint32_t)layer;
  tf2x32(0u, 4347u, k0, k1);
  // random_bits partitionable: element i (64-bit ctr) -> (hi,lo)=(0,i); xor outs
  uint32_t x0 = 0u, x1 = i;
  tf2x32(k0, k1, x0, x1);
  masks[gid] = bern_mask(x0 ^ x1);
}

// ---------------- K3: input-projection GEMM ----------------
// A[262144][128] (dtype AM), W f32 [128][4*NT], per-gate mask on A rows.
// Z f16 [262144][4*NT]. 128-row x NT-col tile per block, K chunks of 32.
template<int NT, int AM>
__global__ __launch_bounds__(256) void gemm_zin(
    const void*  __restrict__ A,
    const float* __restrict__ W,
    const float* __restrict__ bias,
    const float* __restrict__ maskL,   // this layer's masks [4][256][128]
    __half* __restrict__ Z)
{
  constexpr int WCOLS = 4*NT;
  constexpr int CT = NT/16;            // cols per thread (8 or 4)
  __shared__ float As[128][33];        // +1 pad: conflict-free column reads
  __shared__ float Ws[32][NT+4];
  const int tid  = threadIdx.x;
  const int r0   = blockIdx.x * 128;   // row tile (1024%128==0 -> single batch)
  const int gate = blockIdx.y;
  const int bb   = blockIdx.x >> 3;    // batch index
  const float* mrow = maskL + gate*32768 + bb*128;
  const int tr = tid >> 4, tc = tid & 15;

  float acc[8][CT];
  #pragma unroll
  for (int i=0;i<8;i++)
    #pragma unroll
    for (int j=0;j<CT;j++) acc[i][j] = 0.f;

  for (int kc=0; kc<4; ++kc){
    // stage A chunk [128 x 32], masked, f32
    #pragma unroll
    for (int vv=0; vv<2; ++vv){
      int v = tid + 256*vv;
      int r = v >> 2;
      int d = (v & 3) << 3;
      float av[8];
      cvt8<AM>(A, (size_t)(r0 + r)*128 + kc*32 + d, av);
      const float* mp = mrow + kc*32 + d;
      float4 m0 = *(const float4*)mp;
      float4 m1 = *(const float4*)(mp + 4);
      float* dst = &As[r][d];
      dst[0]=av[0]*m0.x; dst[1]=av[1]*m0.y; dst[2]=av[2]*m0.z; dst[3]=av[3]*m0.w;
      dst[4]=av[4]*m1.x; dst[5]=av[5]*m1.y; dst[6]=av[6]*m1.z; dst[7]=av[7]*m1.w;
    }
    // stage W chunk [32 x NT]
    constexpr int WV = (32*NT)/(256*8);
    #pragma unroll
    for (int vv=0; vv<WV; ++vv){
      int v = tid + 256*vv;
      int f = v*8;
      int k = f / NT;
      int n = f - k*NT;
      float wv[8];
      cvt8<MODE_F32>(W, (size_t)(kc*32 + k)*WCOLS + gate*NT + n, wv);
      float* dst = &Ws[k][n];
      #pragma unroll
      for (int q=0;q<8;q++) dst[q] = wv[q];
    }
    __syncthreads();
    #pragma unroll 4
    for (int k=0;k<32;k++){
      float a[8];
      #pragma unroll
      for (int i=0;i<8;i++) a[i] = As[tr*8+i][k];
      float w[CT];
      const float4* wp = (const float4*)&Ws[k][tc*CT];
      float4 w0 = wp[0];
      w[0]=w0.x; w[1]=w0.y; w[2]=w0.z; w[3]=w0.w;
      if constexpr (CT == 8){
        float4 w1 = wp[1];
        w[4]=w1.x; w[5]=w1.y; w[6]=w1.z; w[7]=w1.w;
      }
      #pragma unroll
      for (int i=0;i<8;i++)
        #pragma unroll
        for (int j=0;j<CT;j++) acc[i][j] = fmaf(a[i], w[j], acc[i][j]);
    }
    __syncthreads();
  }
  // epilogue: + bias, store f16 (vectorized)
  float bj[CT];
  #pragma unroll
  for (int j=0;j<CT;j++) bj[j] = bias[gate*NT + tc*CT + j];
  #pragma unroll
  for (int i=0;i<8;i++){
    union { __half h[8]; uint4 u4; uint2 u2; } pk;
    #pragma unroll
    for (int j=0;j<CT;j++) pk.h[j] = __float2half(acc[i][j] + bj[j]);
    size_t idx = (size_t)(r0 + tr*8 + i)*WCOLS + gate*NT + tc*CT;
    if constexpr (CT == 8) *(uint4*)(Z + idx) = pk.u4;
    else                   *(uint2*)(Z + idx) = pk.u2;
  }
}

// ---------------- K4: persistent recurrence ----------------
__device__ __forceinline__ float sigf(float x){ return 1.0f/(1.0f + __expf(-x)); }
__device__ __forceinline__ float tanh_f(float x){ return 1.0f - 2.0f/(__expf(2.0f*x) + 1.0f); }

// 1 block per batch row; thread c owns output column c (= gate*U + u).
// Wr column in VGPRs (U floats); h broadcast from LDS; z_in streamed (prefetch).
template<int U, bool SEQ>
__global__ __launch_bounds__(4*U) void rec_kernel(
    const __half* __restrict__ Zin,     // [256][1024][4U]
    const float*  __restrict__ Wr,      // [U][4U]
    __half* __restrict__ Hseq,          // [256][1024][U]  (SEQ)
    float*  __restrict__ Hlast)         // [256][U]        (!SEQ, f32 out)
{
  constexpr int C = 4*U;
  const int row = blockIdx.x;
  const int c   = threadIdx.x;
  float w[U];
  #pragma unroll
  for (int d=0; d<U; ++d) w[d] = Wr[(size_t)d*C + c];

  __shared__ __align__(16) float h_lds[U];
  __shared__ float z_lds[C];
  if (c < U) h_lds[c] = 0.0f;
  float cst = 0.0f;
  __syncthreads();

  const __half* zp = Zin + (size_t)row*1024*C + c;
  float znext = __half2float(zp[0]);
  for (int t=0; t<1024; ++t){
    float acc = znext;                               // z_in (+bias, from GEMM)
    if (t + 1 < 1024) znext = __half2float(zp[(size_t)(t+1)*C]);  // prefetch
    const float4* h4 = (const float4*)h_lds;
    #pragma unroll
    for (int q=0; q<U/4; ++q){
      float4 hv = h4[q];                             // uniform -> LDS broadcast
      acc = fmaf(w[4*q+0], hv.x, acc);
      acc = fmaf(w[4*q+1], hv.y, acc);
      acc = fmaf(w[4*q+2], hv.z, acc);
      acc = fmaf(w[4*q+3], hv.w, acc);
    }
    z_lds[c] = acc;
    __syncthreads();
    if (c < U){
      float zi = z_lds[c],     zf = z_lds[U+c];
      float zg = z_lds[2*U+c], zo = z_lds[3*U+c];
      float gi = sigf(zi), gf = sigf(zf), gg = tanh_f(zg), go = sigf(zo);
      cst = fmaf(gf, cst, gi*gg);
      float h = go * tanh_f(cst);
      h_lds[c] = h;
      if constexpr (SEQ){
        Hseq[((size_t)row*1024 + t)*U + c] = __float2half(h);
      } else {
        if (t == 1023) Hlast[(size_t)row*U + c] = h;
      }
    }
    __syncthreads();
  }
}

// ---------------- host launch ----------------
extern "C" void kernel_launch(void* const* d_in, const int* in_sizes, int n_in,
                              void* d_out, int out_size, void* d_ws, size_t ws_size,
                              hipStream_t stream)
{
  (void)in_sizes; (void)n_in; (void)out_size; (void)ws_size;
  const void*  x   = d_in[0];
  const float* Wk0 = (const float*)d_in[1];
  const float* Wr0 = (const float*)d_in[2];
  const float* b0  = (const float*)d_in[3];
  const float* Wk1 = (const float*)d_in[4];
  const float* Wr1 = (const float*)d_in[5];
  const float* b1  = (const float*)d_in[6];
  const float* Wko = (const float*)d_in[7];
  const float* Wro = (const float*)d_in[8];
  const float* bo  = (const float*)d_in[9];

  char* ws = (char*)d_ws;
  float*  masks = (float*)(ws + 256);                           // 1.5 MB
  __half* zin   = (__half*)(ws + 256 + 3*131072*4);             // 256 MB
  __half* h0    = (__half*)((char*)zin + (size_t)262144*512*2); // 64 MB
  __half* h1    = h0 + (size_t)262144*128;                      // 64 MB
  float*  out   = (float*)d_out;

  mask_kernel<<<1536, 256, 0, stream>>>(masks);

  // layer 0 (A = x, f32)
  gemm_zin<128, MODE_F32><<<dim3(2048,4), 256, 0, stream>>>(x, Wk0, b0, masks, zin);
  rec_kernel<128, true><<<256, 512, 0, stream>>>(zin, Wr0, h0, nullptr);
  // layer 1 (A = h0, f16 ours)
  gemm_zin<128, MODE_F16><<<dim3(2048,4), 256, 0, stream>>>(h0, Wk1, b1, masks + 131072, zin);
  rec_kernel<128, true><<<256, 512, 0, stream>>>(zin, Wr1, h1, nullptr);
  // layer 2 (output, U=64, last state only, f32 out)
  gemm_zin<64, MODE_F16><<<dim3(2048,4), 256, 0, stream>>>(h1, Wko, bo, masks + 262144, zin);
  rec_kernel<64, false><<<256, 256, 0, stream>>>(zin, Wro, nullptr, out);
}